// Round 5
// baseline (3198.102 us; speedup 1.0000x reference)
//
#include <hip/hip_runtime.h>

#define NB 16
#define WD 17
#define NPIX 289
#define PWD 19
#define PPIX 361   // 19*19 zero-padded
#define FWD 21
#define FPIX 441   // 21*21 zero-padded food
#define NT 512     // 8 waves; each wave owns 37 pixels AND all 64 hidden (8/lane-group)

typedef float v2f __attribute__((ext_vector_type(2)));

__device__ __forceinline__ v2f vfma2(v2f a, v2f b, v2f c) {
  return __builtin_elementwise_fma(a, b, c);
}

template<int CTRL>
__device__ __forceinline__ float dpp_add(float v) {
  int t = __builtin_amdgcn_update_dpp(0, __float_as_int(v), CTRL, 0xF, 0xF, false);
  return v + __int_as_float(t);
}
__device__ __forceinline__ float grp8_sum(float v) {
  v = dpp_add<0xB1>(v);   // quad_perm(1,0,3,2): xor 1
  v = dpp_add<0x4E>(v);   // quad_perm(2,3,0,1): xor 2
  int t = __builtin_amdgcn_ds_swizzle(__float_as_int(v), 0x101F); // xor 4
  return v + __int_as_float(t);
}
__device__ __forceinline__ int pp_of(int q) {
  int qy = q / WD;
  return (qy + 1) * PWD + (q - qy * WD) + 1;
}

__global__ __launch_bounds__(NT)
__attribute__((amdgpu_waves_per_eu(2, 2)))
void ca_kernel(
    const float* __restrict__ cell_in, const float* __restrict__ food_in,
    const int* __restrict__ steps_in,
    const float* __restrict__ fc1_w, const float* __restrict__ fc1_b,
    const float* __restrict__ fc2_w, const float* __restrict__ fc2_b,
    float* __restrict__ out)
{
  __shared__ float4 s_cellv[PPIX];            // (ch0_premask-kept? no: post-clip pre-KEEP ch0, ch1, ch2, scent)
  __shared__ float  s_x0[PPIX];               // raw x0 plane (borders 0)
  __shared__ __align__(16) float s_v[320];    // post-clip pre-keep ch0; [289..320)=0
  __shared__ float4 s_xv[320];                // (x0,x1,x2,x3) per pixel
  __shared__ float4 s_dxv[320];               // y4..7  (Sobel-x of post-keep cell)
  __shared__ float4 s_dyv[320];               // y8..11
  __shared__ float  s_food[FPIX];
  __shared__ int    s_redbuf[2][8];           // double-buffered per-wave alive counts
  __shared__ float  s_sum[8];

  const int b    = blockIdx.x;
  const int tid  = threadIdx.x;
  const int lane = tid & 63;
  const int wv   = tid >> 6;
  const int p    = wv * 37 + lane;            // owner pixel
  const bool act = (lane < 37) && (p < NPIX);
  const int pv   = act ? p : 0;
  const int py   = pv / WD, px = pv - py * WD;
  const int pp   = (py + 1) * PWD + px + 1;
  const int fp   = (py + 2) * FWD + px + 2;

  // ---------------- init ----------------
  for (int i = tid; i < PPIX; i += NT) { float4 z; z.x=z.y=z.z=z.w=0.f; s_cellv[i]=z; }
  for (int i = tid; i < PPIX; i += NT) s_x0[i] = 0.f;
  for (int i = tid; i < 320;  i += NT) s_v[i] = 0.f;
  for (int i = tid; i < 320;  i += NT) { float4 z; z.x=z.y=z.z=z.w=0.f; s_dxv[i]=z; s_dyv[i]=z; }
  for (int i = tid; i < FPIX; i += NT) s_food[i] = 0.f;
  if (tid < 16) s_redbuf[tid >> 3][tid & 7] = 0;
  __syncthreads();

  float o0m = 0.f, o1m = 0.f, o2m = 0.f, o3m = 0.f;
  if (act) {
    const float* cb = cell_in + (size_t)b * (4 * NPIX);
    o0m = cb[p]; o1m = cb[NPIX + p]; o2m = cb[2 * NPIX + p]; o3m = cb[3 * NPIX + p];
    s_food[fp] = food_in[(size_t)b * NPIX + p];
  }

  // weights -> VGPRs, LANE-VARYING (units 8*(lane&7)..+8) so they can't be
  // SGPR-ized or cheaply rematerialized; loaded once from global.
  const int Lb = (lane & 7) * 8;
  v2f w1p[8][6]; float b1s[8]; v2f w2a[8], w2b[8];
  #pragma unroll
  for (int j = 0; j < 8; ++j) {
    const int h = Lb + j;
    const float4* wr = (const float4*)(fc1_w + h * 12);
    float4 r0 = wr[0], r1 = wr[1], r2 = wr[2];
    w1p[j][0].x=r0.x; w1p[j][0].y=r0.y;
    w1p[j][1].x=r0.z; w1p[j][1].y=r0.w;
    w1p[j][2].x=r1.x; w1p[j][2].y=r1.y;
    w1p[j][3].x=r1.z; w1p[j][3].y=r1.w;
    w1p[j][4].x=r2.x; w1p[j][4].y=r2.y;
    w1p[j][5].x=r2.z; w1p[j][5].y=r2.w;
    b1s[j] = fc1_b[h];
    w2a[j].x = fc2_w[0 * 64 + h]; w2a[j].y = fc2_w[1 * 64 + h];
    w2b[j].x = fc2_w[2 * 64 + h]; w2b[j].y = fc2_w[3 * 64 + h];
  }
  const float b20 = fc2_b[0], b21 = fc2_b[1], b22 = fc2_b[2], b23 = fc2_b[3];
  __syncthreads();

  // scent = conv5x5(food), constant; stage in s_x0 to get its Sobel
  float scent = 0.f;
  if (act) {
    const float w5[5][5] = {
      {0.f,0.125f,0.25f,0.125f,0.f},
      {0.125f,0.25f,0.5f,0.25f,0.125f},
      {0.25f,0.5f,1.0f,0.5f,0.25f},
      {0.125f,0.25f,0.5f,0.25f,0.125f},
      {0.f,0.125f,0.25f,0.125f,0.f}};
    #pragma unroll
    for (int ky = 0; ky < 5; ++ky)
      #pragma unroll
      for (int kx = 0; kx < 5; ++kx)
        if (w5[ky][kx] != 0.f)
          scent = fmaf(w5[ky][kx], s_food[fp + (ky - 2) * FWD + kx - 2], scent);
    s_x0[pp] = scent;
    float4 cv; cv.x = o0m; cv.y = o1m; cv.z = o2m; cv.w = scent;
    s_cellv[pp] = cv;
  }
  __syncthreads();

  float dxs = 0.f, dys = 0.f;
  if (act) {
    const int q = pp;
    float t00=s_x0[q-PWD-1], t01=s_x0[q-PWD], t02=s_x0[q-PWD+1];
    float t10=s_x0[q-1],                      t12=s_x0[q+1];
    float t20=s_x0[q+PWD-1], t21=s_x0[q+PWD], t22=s_x0[q+PWD+1];
    dxs = ((t02-t00)+2.f*(t12-t10)+(t22-t20))*0.125f;
    dys = ((t20-t00)+2.f*(t21-t01)+(t22-t02))*0.125f;
  }
  __syncthreads();

  const int steps = steps_in[0];
  bool pre = false;

  // exact kth-largest bits via 2-bit radix descend (ballot-based, wave-redundant)
  auto do_select = [&](int par) -> unsigned {
    const int4 ra = ((const int4*)&s_redbuf[par][0])[0];
    const int4 rb = ((const int4*)&s_redbuf[par][0])[1];
    int kc = ra.x + ra.y + ra.z + ra.w + rb.x + rb.y + rb.z + rb.w;
    int k_idx = kc - 1; if (k_idx < 0) k_idx += NPIX;   // torch wrap
    if (k_idx >= NPIX - 1) return 0u;                    // keep-all
    const unsigned k = (unsigned)(k_idx + 1);
    const uint4 va = ((const uint4*)s_v)[lane];
    const unsigned vb = ((const unsigned*)s_v)[256 + lane];
    auto cnt5 = [&](unsigned cand) -> unsigned {
      return (unsigned)__popcll(__ballot(va.x >= cand))
           + (unsigned)__popcll(__ballot(va.y >= cand))
           + (unsigned)__popcll(__ballot(va.z >= cand))
           + (unsigned)__popcll(__ballot(va.w >= cand))
           + (unsigned)__popcll(__ballot(vb   >= cand));
    };
    unsigned t = 0;
    for (int bb = 28; bb >= 0; bb -= 2) {
      unsigned c1 = t | (1u << bb), c2 = t | (2u << bb), c3 = t | (3u << bb);
      unsigned n1 = cnt5(c1), n2 = cnt5(c2), n3 = cnt5(c3);
      t = (n3 >= k) ? c3 : ((n2 >= k) ? c2 : ((n1 >= k) ? c1 : t));
    }
    return t;
  };

  for (int s = 0; s < steps; ++s) {
    // ---- phase 1: select kth; stencil+Sobel (keep applied inline); MLP ----
    const unsigned kth = do_select(s & 1);

    bool alive = false;
    if (act) {
      const int q = pp;
      float4 n00=s_cellv[q-PWD-1], n01=s_cellv[q-PWD], n02=s_cellv[q-PWD+1];
      float4 n10=s_cellv[q-1],                          n12=s_cellv[q+1];
      float4 n20=s_cellv[q+PWD-1], n21=s_cellv[q+PWD], n22=s_cellv[q+PWD+1];
      float k00=(__float_as_uint(n00.x)>=kth)?n00.x:0.f;
      float k01=(__float_as_uint(n01.x)>=kth)?n01.x:0.f;
      float k02=(__float_as_uint(n02.x)>=kth)?n02.x:0.f;
      float k10=(__float_as_uint(n10.x)>=kth)?n10.x:0.f;
      float k12=(__float_as_uint(n12.x)>=kth)?n12.x:0.f;
      float k20=(__float_as_uint(n20.x)>=kth)?n20.x:0.f;
      float k21=(__float_as_uint(n21.x)>=kth)?n21.x:0.f;
      float k22=(__float_as_uint(n22.x)>=kth)?n22.x:0.f;
      float o0k=(__float_as_uint(o0m)>=kth)?o0m:0.f;
      float mx = fmaxf(fmaxf(fmaxf(fmaxf(k00,k01),fmaxf(k02,k10)),
                             fmaxf(fmaxf(o0k,k12),fmaxf(k20,k21))), k22);
      pre = mx > 0.1f;
      float4 dxq, dyq;
      dxq.x = ((k02-k00)+2.f*(k12-k10)+(k22-k20))*0.125f;
      dxq.y = ((n02.y-n00.y)+2.f*(n12.y-n10.y)+(n22.y-n20.y))*0.125f;
      dxq.z = ((n02.z-n00.z)+2.f*(n12.z-n10.z)+(n22.z-n20.z))*0.125f;
      dxq.w = dxs;
      dyq.x = ((k20-k00)+2.f*(k21-k01)+(k22-k02))*0.125f;
      dyq.y = ((n20.y-n00.y)+2.f*(n21.y-n01.y)+(n22.y-n02.y))*0.125f;
      dyq.z = ((n20.z-n00.z)+2.f*(n21.z-n01.z)+(n22.z-n02.z))*0.125f;
      dyq.w = dys;
      s_dxv[p] = dxq; s_dyv[p] = dyq;     // intra-wave consumer only (no barrier needed)
      alive = o0k > 0.1f;
    }
    {
      unsigned long long m = __ballot(alive);
      if (lane == 0) s_redbuf[(s + 1) & 1][wv] = (int)__popcll(m);
    }

    // MLP: 5 passes, 8 pixels/pass, 8-lane group per pixel, 8 hidden/lane
    #pragma unroll 1
    for (int pass = 0; pass < 5; ++pass) {
      const int slot = pass * 8 + (lane >> 3);
      const int bp   = wv * 37 + slot;
      const int q    = (bp < NPIX) ? bp : 0;
      const int qpp  = pp_of(q);
      float4 cv  = s_cellv[qpp];
      float4 dx4 = s_dxv[q];
      float4 dy4 = s_dyv[q];
      float y0 = (__float_as_uint(cv.x) >= kth) ? cv.x : 0.f;
      v2f y01; y01.x=y0;    y01.y=cv.y;
      v2f y23; y23.x=cv.z;  y23.y=cv.w;
      v2f y45; y45.x=dx4.x; y45.y=dx4.y;
      v2f y67; y67.x=dx4.z; y67.y=dx4.w;
      v2f y89; y89.x=dy4.x; y89.y=dy4.y;
      v2f yab; yab.x=dy4.z; yab.y=dy4.w;
      v2f a01, a23; a01.x=0.f; a01.y=0.f; a23.x=0.f; a23.y=0.f;
      #pragma unroll
      for (int j = 0; j < 8; ++j) {
        v2f a; a.x = b1s[j]; a.y = 0.f;
        a = vfma2(w1p[j][0], y01, a);
        a = vfma2(w1p[j][1], y23, a);
        a = vfma2(w1p[j][2], y45, a);
        a = vfma2(w1p[j][3], y67, a);
        a = vfma2(w1p[j][4], y89, a);
        a = vfma2(w1p[j][5], yab, a);
        float g = fmaxf(a.x + a.y, 0.f);
        v2f gg; gg.x = g; gg.y = g;
        a01 = vfma2(w2a[j], gg, a01);
        a23 = vfma2(w2b[j], gg, a23);
      }
      float d0 = grp8_sum(a01.x);
      float d1 = grp8_sum(a01.y);
      float d2 = grp8_sum(a23.x);
      float d3 = grp8_sum(a23.y);
      if ((lane & 7) == 0 && slot < 37 && bp < NPIX) {
        float x0v = y0   + d0 + b20;
        float x1v = cv.y + d1 + b21;
        float x2v = cv.z + d2 + b22;
        float x3v = cv.w + d3 + b23;
        s_x0[qpp] = x0v;
        float4 xv; xv.x=x0v; xv.y=x1v; xv.z=x2v; xv.w=x3v;
        s_xv[bp] = xv;
      }
    }
    __syncthreads();

    // ---- phase 2: post-mask maxpool, clip, commit cell + s_v ----
    if (act) {
      float4 xv = s_xv[p];
      const int q = pp;
      float m0 = fmaxf(fmaxf(fmaxf(fmaxf(s_x0[q-PWD-1],s_x0[q-PWD]),
                                   fmaxf(s_x0[q-PWD+1],s_x0[q-1])),
                             fmaxf(fmaxf(xv.x,s_x0[q+1]),
                                   fmaxf(s_x0[q+PWD-1],s_x0[q+PWD]))), s_x0[q+PWD+1]);
      bool km = pre && (m0 > 0.1f);
      o0m = km ? fminf(fmaxf(xv.x,   0.f),  1.f) : 0.f;  // clip[-10,10]∘[0,1] == [0,1]
      o1m = km ? fminf(fmaxf(xv.y, -10.f), 10.f) : 0.f;
      o2m = km ? fminf(fmaxf(xv.z, -10.f), 10.f) : 0.f;
      o3m = km ? fminf(fmaxf(xv.w, -10.f), 10.f) : 0.f;
      s_v[p] = o0m;
      float4 cw; cw.x = o0m; cw.y = o1m; cw.z = o2m; cw.w = scent;
      s_cellv[pp] = cw;
    }
    __syncthreads();
  }

  // ---- epilogue: final keep + outputs ----
  const unsigned kthf = do_select(steps & 1);
  float o0f = 0.f;
  bool alive = false;
  if (act) {
    o0f = (__float_as_uint(o0m) >= kthf) ? o0m : 0.f;
    alive = o0f > 0.1f;
    float* oc = out + (size_t)b * (4 * NPIX);
    oc[p] = o0f; oc[NPIX + p] = o1m; oc[2*NPIX + p] = o2m; oc[3*NPIX + p] = o3m;
    out[NB*4*NPIX + (size_t)b * NPIX + p] = food_in[(size_t)b * NPIX + p];
  }
  {
    unsigned long long m = __ballot(alive);
    if (lane == 0) s_redbuf[0][wv] = (int)__popcll(m);
  }
  float sv = o0f;
  #pragma unroll
  for (int off = 32; off > 0; off >>= 1) sv += __shfl_down(sv, off, 64);
  if (lane == 0) s_sum[wv] = sv;
  __syncthreads();
  if (tid == 0) {
    float tot = 0.f; int kc = 0;
    #pragma unroll
    for (int w = 0; w < 8; ++w) { tot += s_sum[w]; kc += s_redbuf[0][w]; }
    out[NB*4*NPIX + NB*NPIX + b]      = tot;
    out[NB*4*NPIX + NB*NPIX + NB + b] = (float)kc;
  }
}

extern "C" void kernel_launch(void* const* d_in, const int* in_sizes, int n_in,
                              void* d_out, int out_size, void* d_ws, size_t ws_size,
                              hipStream_t stream) {
  (void)in_sizes; (void)n_in; (void)d_ws; (void)ws_size; (void)out_size;
  ca_kernel<<<dim3(NB), dim3(NT), 0, stream>>>(
      (const float*)d_in[0], (const float*)d_in[1], (const int*)d_in[2],
      (const float*)d_in[3], (const float*)d_in[4], (const float*)d_in[5],
      (const float*)d_in[6], (float*)d_out);
}

// Round 6
// 3026.999 us; speedup vs baseline: 1.0565x; 1.0565x over previous
//
#include <hip/hip_runtime.h>

#define NB 16
#define WD 17
#define NPIX 289
#define PWD 19
#define PPIX 361   // 19*19 zero-padded
#define FWD 21
#define FPIX 441   // 21*21 zero-padded food
#define NT 512     // 8 waves, 2/SIMD; wave owns 37 pixels + 8 hidden units

typedef float v2f __attribute__((ext_vector_type(2)));

__device__ __forceinline__ v2f vfma2(v2f a, v2f b, v2f c) {
  return __builtin_elementwise_fma(a, b, c);
}
// Pin a value into a VGPR: opaque asm def — cannot be rematerialized from
// LDS/global and strongly discourages scratch spill. (R4/R5 showed the
// compiler otherwise re-reads weights every MLP pass: VGPR_Count 104-112.)
#define PINV(x) asm volatile("" : "+v"(x))

__global__ __launch_bounds__(NT)
__attribute__((amdgpu_waves_per_eu(2, 2)))
void ca_kernel(
    const float* __restrict__ cell_in, const float* __restrict__ food_in,
    const int* __restrict__ steps_in,
    const float* __restrict__ fc1_w, const float* __restrict__ fc1_b,
    const float* __restrict__ fc2_w, const float* __restrict__ fc2_b,
    float* __restrict__ out)
{
  __shared__ float4 s_cellv[PPIX];            // committed pre-keep (ch0,ch1,ch2,scent)
  __shared__ float  s_x0[PPIX];               // raw x0 plane (borders 0)
  __shared__ __align__(16) float s_v[320];    // committed pre-keep ch0; [289..320)=0
  __shared__ float4 s_y0[320], s_y1[320], s_y2[320];  // per-pixel y (12 floats)
  __shared__ float4 s_pd[8][320];             // per-wave partial deltas
  __shared__ float  s_food[FPIX];
  __shared__ float  s_w[1088];                // fc1_w 768 | fc1_b 64 | fc2_w 256
  __shared__ int    s_redbuf[2][8];           // double-buffered alive counts
  __shared__ float  s_sum[8];

  const int b    = blockIdx.x;
  const int tid  = threadIdx.x;
  const int lane = tid & 63;
  const int wv   = tid >> 6;
  const int p    = wv * 37 + lane;            // owner pixel
  const bool act = (lane < 37) && (p < NPIX);
  const int pv   = act ? p : 0;
  const int py   = pv / WD, px = pv - py * WD;
  const int pp   = (py + 1) * PWD + px + 1;
  const int fp   = (py + 2) * FWD + px + 2;

  // ---------------- init ----------------
  for (int i = tid; i < PPIX; i += NT) { float4 z; z.x=z.y=z.z=z.w=0.f; s_cellv[i]=z; }
  for (int i = tid; i < PPIX; i += NT) s_x0[i] = 0.f;
  for (int i = tid; i < 320;  i += NT) s_v[i] = 0.f;
  for (int i = tid; i < 320;  i += NT) { float4 z; z.x=z.y=z.z=z.w=0.f; s_y0[i]=z; s_y1[i]=z; s_y2[i]=z; }
  for (int i = tid; i < FPIX; i += NT) s_food[i] = 0.f;
  for (int i = tid; i < 768;  i += NT) s_w[i] = fc1_w[i];
  for (int i = tid; i < 64;   i += NT) s_w[768 + i] = fc1_b[i];
  for (int i = tid; i < 256;  i += NT) s_w[832 + i] = fc2_w[i];
  if (tid < 16) s_redbuf[tid >> 3][tid & 7] = 0;
  __syncthreads();

  float o0m = 0.f, o1m = 0.f, o2m = 0.f, o3m = 0.f;
  if (act) {
    const float* cb = cell_in + (size_t)b * (4 * NPIX);
    o0m = cb[p]; o1m = cb[NPIX + p]; o2m = cb[2 * NPIX + p]; o3m = cb[3 * NPIX + p];
    s_food[fp] = food_in[(size_t)b * NPIX + p];
  }
  __syncthreads();

  // weights -> VGPRs once (wave wv owns hidden [8wv,8wv+8)); then PIN.
  const int h0 = wv * 8;
  v2f w1p[8][6], b1v[8], w2a[8], w2b[8];
  #pragma unroll
  for (int j = 0; j < 8; ++j) {
    const int h = h0 + j;
    #pragma unroll
    for (int dd = 0; dd < 6; ++dd) {
      v2f w; w.x = s_w[h * 12 + 2 * dd]; w.y = s_w[h * 12 + 2 * dd + 1];
      w1p[j][dd] = w;
    }
    v2f bb; bb.x = s_w[768 + h]; bb.y = 0.f; b1v[j] = bb;
    v2f wa; wa.x = s_w[832 + 0 * 64 + h]; wa.y = s_w[832 + 1 * 64 + h]; w2a[j] = wa;
    v2f wb; wb.x = s_w[832 + 2 * 64 + h]; wb.y = s_w[832 + 3 * 64 + h]; w2b[j] = wb;
  }
  #pragma unroll
  for (int j = 0; j < 8; ++j) {
    #pragma unroll
    for (int dd = 0; dd < 6; ++dd) PINV(w1p[j][dd]);
    PINV(b1v[j]); PINV(w2a[j]); PINV(w2b[j]);
  }
  const float b20 = fc2_b[0], b21 = fc2_b[1], b22 = fc2_b[2], b23 = fc2_b[3];

  // scent = conv5x5(food), constant; stage in s_x0 for its Sobel
  float scent = 0.f;
  if (act) {
    const float w5[5][5] = {
      {0.f,0.125f,0.25f,0.125f,0.f},
      {0.125f,0.25f,0.5f,0.25f,0.125f},
      {0.25f,0.5f,1.0f,0.5f,0.25f},
      {0.125f,0.25f,0.5f,0.25f,0.125f},
      {0.f,0.125f,0.25f,0.125f,0.f}};
    #pragma unroll
    for (int ky = 0; ky < 5; ++ky)
      #pragma unroll
      for (int kx = 0; kx < 5; ++kx)
        if (w5[ky][kx] != 0.f)
          scent = fmaf(w5[ky][kx], s_food[fp + (ky - 2) * FWD + kx - 2], scent);
    s_x0[pp] = scent;
    float4 cv; cv.x = o0m; cv.y = o1m; cv.z = o2m; cv.w = scent;
    s_cellv[pp] = cv;
  }
  __syncthreads();

  float dxs = 0.f, dys = 0.f;
  if (act) {
    const int q = pp;
    float t00=s_x0[q-PWD-1], t01=s_x0[q-PWD], t02=s_x0[q-PWD+1];
    float t10=s_x0[q-1],                      t12=s_x0[q+1];
    float t20=s_x0[q+PWD-1], t21=s_x0[q+PWD], t22=s_x0[q+PWD+1];
    dxs = ((t02-t00)+2.f*(t12-t10)+(t22-t20))*0.125f;
    dys = ((t20-t00)+2.f*(t21-t01)+(t22-t02))*0.125f;
    s_x0[pp] = 0.f;                      // restore zero plane for step loop
  }
  {
    unsigned long long m = __ballot(act && (o0m > 0.1f));
    if (lane == 0) s_redbuf[0][wv] = (int)__popcll(m);
  }
  __syncthreads();

  const int steps = steps_in[0];
  bool pre = false;
  float o0k = 0.f;

  // exact kth-largest bits: 2-bit radix descend over uint-ordered nonneg floats
  auto do_select = [&](int par) -> unsigned {
    const int4 ra = ((const int4*)&s_redbuf[par][0])[0];
    const int4 rb = ((const int4*)&s_redbuf[par][0])[1];
    int kc = ra.x + ra.y + ra.z + ra.w + rb.x + rb.y + rb.z + rb.w;
    int k_idx = kc - 1; if (k_idx < 0) k_idx += NPIX;   // torch wrap
    if (k_idx >= NPIX - 1) return 0u;                    // keep-all
    const unsigned k = (unsigned)(k_idx + 1);
    const uint4 va = ((const uint4*)s_v)[lane];
    const unsigned vb = ((const unsigned*)s_v)[256 + lane];
    auto cnt5 = [&](unsigned cand) -> unsigned {
      return (unsigned)__popcll(__ballot(va.x >= cand))
           + (unsigned)__popcll(__ballot(va.y >= cand))
           + (unsigned)__popcll(__ballot(va.z >= cand))
           + (unsigned)__popcll(__ballot(va.w >= cand))
           + (unsigned)__popcll(__ballot(vb   >= cand));
    };
    unsigned t = 0;
    #pragma unroll 1
    for (int bb = 28; bb >= 0; bb -= 2) {
      unsigned c1 = t | (1u << bb), c2 = t | (2u << bb), c3 = t | (3u << bb);
      unsigned n1 = cnt5(c1), n2 = cnt5(c2), n3 = cnt5(c3);
      t = (n3 >= k) ? c3 : ((n2 >= k) ? c2 : ((n1 >= k) ? c1 : t));
    }
    return t;
  };

  for (int s = 0; s < steps; ++s) {
    // ---- A: select kth; keep applied inline; stencil -> y; alive ballot ----
    const unsigned kth = do_select(s & 1);
    bool alive = false;
    if (act) {
      const int q = pp;
      float4 n00=s_cellv[q-PWD-1], n01=s_cellv[q-PWD], n02=s_cellv[q-PWD+1];
      float4 n10=s_cellv[q-1],                          n12=s_cellv[q+1];
      float4 n20=s_cellv[q+PWD-1], n21=s_cellv[q+PWD], n22=s_cellv[q+PWD+1];
      float k00=(__float_as_uint(n00.x)>=kth)?n00.x:0.f;
      float k01=(__float_as_uint(n01.x)>=kth)?n01.x:0.f;
      float k02=(__float_as_uint(n02.x)>=kth)?n02.x:0.f;
      float k10=(__float_as_uint(n10.x)>=kth)?n10.x:0.f;
      float k12=(__float_as_uint(n12.x)>=kth)?n12.x:0.f;
      float k20=(__float_as_uint(n20.x)>=kth)?n20.x:0.f;
      float k21=(__float_as_uint(n21.x)>=kth)?n21.x:0.f;
      float k22=(__float_as_uint(n22.x)>=kth)?n22.x:0.f;
      o0k = (__float_as_uint(o0m)>=kth)?o0m:0.f;
      float mx = fmaxf(fmaxf(fmaxf(fmaxf(k00,k01),fmaxf(k02,k10)),
                             fmaxf(fmaxf(o0k,k12),fmaxf(k20,k21))), k22);
      pre = mx > 0.1f;
      float4 q0; q0.x=o0k; q0.y=o1m; q0.z=o2m; q0.w=scent;
      float4 dxq, dyq;
      dxq.x = ((k02-k00)+2.f*(k12-k10)+(k22-k20))*0.125f;
      dxq.y = ((n02.y-n00.y)+2.f*(n12.y-n10.y)+(n22.y-n20.y))*0.125f;
      dxq.z = ((n02.z-n00.z)+2.f*(n12.z-n10.z)+(n22.z-n20.z))*0.125f;
      dxq.w = dxs;
      dyq.x = ((k20-k00)+2.f*(k21-k01)+(k22-k02))*0.125f;
      dyq.y = ((n20.y-n00.y)+2.f*(n21.y-n01.y)+(n22.y-n02.y))*0.125f;
      dyq.z = ((n20.z-n00.z)+2.f*(n21.z-n01.z)+(n22.z-n02.z))*0.125f;
      dyq.w = dys;
      s_y0[p] = q0; s_y1[p] = dxq; s_y2[p] = dyq;
      alive = o0k > 0.1f;
    }
    {
      unsigned long long m = __ballot(alive);
      if (lane == 0) s_redbuf[(s + 1) & 1][wv] = (int)__popcll(m);
    }
    __syncthreads();

    // ---- B: hidden-parallel MLP, pinned VGPR weights, packed fp32 ----
    #pragma unroll 1
    for (int c = 0; c < 5; ++c) {
      const int qx = c * 64 + lane;        // 0..319; rows >=289 are zero
      float4 q0 = s_y0[qx], q1 = s_y1[qx], q2 = s_y2[qx];
      v2f y01; y01.x=q0.x; y01.y=q0.y;
      v2f y23; y23.x=q0.z; y23.y=q0.w;
      v2f y45; y45.x=q1.x; y45.y=q1.y;
      v2f y67; y67.x=q1.z; y67.y=q1.w;
      v2f y89; y89.x=q2.x; y89.y=q2.y;
      v2f yab; yab.x=q2.z; yab.y=q2.w;
      v2f a01; a01.x=0.f; a01.y=0.f;
      v2f a23; a23.x=0.f; a23.y=0.f;
      #pragma unroll
      for (int j = 0; j < 8; ++j) {
        v2f a = b1v[j];
        a = vfma2(w1p[j][0], y01, a);
        a = vfma2(w1p[j][1], y23, a);
        a = vfma2(w1p[j][2], y45, a);
        a = vfma2(w1p[j][3], y67, a);
        a = vfma2(w1p[j][4], y89, a);
        a = vfma2(w1p[j][5], yab, a);
        float g = fmaxf(a.x + a.y, 0.f);
        v2f gg; gg.x = g; gg.y = g;
        a01 = vfma2(w2a[j], gg, a01);
        a23 = vfma2(w2b[j], gg, a23);
      }
      if (qx < NPIX) {
        float4 r; r.x=a01.x; r.y=a01.y; r.z=a23.x; r.w=a23.y;
        s_pd[wv][qx] = r;
      }
    }
    __syncthreads();

    // ---- C: sum 8 partials -> x (regs); stage x0 plane ----
    float x0=0.f, x1=0.f, x2=0.f, x3=0.f;
    if (act) {
      float4 d = s_pd[0][p];
      #pragma unroll
      for (int w = 1; w < 8; ++w) {
        float4 t = s_pd[w][p];
        d.x += t.x; d.y += t.y; d.z += t.z; d.w += t.w;
      }
      x0 = o0k + d.x + b20; x1 = o1m + d.y + b21;
      x2 = o2m + d.z + b22; x3 = scent + d.w + b23;
      s_x0[pp] = x0;
    }
    __syncthreads();

    // ---- D: post-mask maxpool, clip, commit pre-keep state ----
    if (act) {
      const int q = pp;
      float m0 = fmaxf(fmaxf(fmaxf(fmaxf(s_x0[q-PWD-1],s_x0[q-PWD]),
                                   fmaxf(s_x0[q-PWD+1],s_x0[q-1])),
                             fmaxf(fmaxf(x0,s_x0[q+1]),
                                   fmaxf(s_x0[q+PWD-1],s_x0[q+PWD]))), s_x0[q+PWD+1]);
      bool km = pre && (m0 > 0.1f);
      o0m = km ? fminf(fmaxf(x0,   0.f),  1.f) : 0.f;  // clip[-10,10]∘[0,1]==[0,1]
      o1m = km ? fminf(fmaxf(x1, -10.f), 10.f) : 0.f;
      o2m = km ? fminf(fmaxf(x2, -10.f), 10.f) : 0.f;
      o3m = km ? fminf(fmaxf(x3, -10.f), 10.f) : 0.f;
      s_v[p] = o0m;
      float4 cw; cw.x = o0m; cw.y = o1m; cw.z = o2m; cw.w = scent;
      s_cellv[pp] = cw;
    }
    __syncthreads();
  }

  // ---- epilogue: final keep + outputs ----
  const unsigned kthf = do_select(steps & 1);
  float o0f = 0.f;
  bool alive = false;
  if (act) {
    o0f = (__float_as_uint(o0m) >= kthf) ? o0m : 0.f;
    alive = o0f > 0.1f;
    float* oc = out + (size_t)b * (4 * NPIX);
    oc[p] = o0f; oc[NPIX + p] = o1m; oc[2*NPIX + p] = o2m; oc[3*NPIX + p] = o3m;
    out[NB*4*NPIX + (size_t)b * NPIX + p] = food_in[(size_t)b * NPIX + p];
  }
  {
    unsigned long long m = __ballot(alive);
    if (lane == 0) s_redbuf[0][wv] = (int)__popcll(m);
  }
  float sv = o0f;
  #pragma unroll
  for (int off = 32; off > 0; off >>= 1) sv += __shfl_down(sv, off, 64);
  if (lane == 0) s_sum[wv] = sv;
  __syncthreads();
  if (tid == 0) {
    float tot = 0.f; int kc = 0;
    #pragma unroll
    for (int w = 0; w < 8; ++w) { tot += s_sum[w]; kc += s_redbuf[0][w]; }
    out[NB*4*NPIX + NB*NPIX + b]      = tot;
    out[NB*4*NPIX + NB*NPIX + NB + b] = (float)kc;
  }
}

extern "C" void kernel_launch(void* const* d_in, const int* in_sizes, int n_in,
                              void* d_out, int out_size, void* d_ws, size_t ws_size,
                              hipStream_t stream) {
  (void)in_sizes; (void)n_in; (void)d_ws; (void)ws_size; (void)out_size;
  ca_kernel<<<dim3(NB), dim3(NT), 0, stream>>>(
      (const float*)d_in[0], (const float*)d_in[1], (const int*)d_in[2],
      (const float*)d_in[3], (const float*)d_in[4], (const float*)d_in[5],
      (const float*)d_in[6], (float*)d_out);
}